// Round 14
// baseline (326.771 us; speedup 1.0000x reference)
//
#include <hip/hip_runtime.h>
#include <hip/hip_bf16.h>
#include <cstdint>

// Problem constants
#define BATCH   16384
#define HDIM    2048
#define HHDIM   1024
#define PDIM    256
#define KNEG    64
#define NBUF    2000
#define M1      (2 * BATCH)          // 32768 rows through the projection head

typedef float  f32x4  __attribute__((ext_vector_type(4)));
typedef __bf16 bf16x8 __attribute__((ext_vector_type(8)));

typedef __attribute__((address_space(3))) unsigned int       lds_u32;
typedef __attribute__((address_space(1))) const unsigned int glb_u32;

__device__ __forceinline__ void gload_lds16(const void* g, void* l) {
  __builtin_amdgcn_global_load_lds((glb_u32*)g, (lds_u32*)l, 16, 0, 0);
}

#define VMCNT(n) asm volatile("s_waitcnt vmcnt(" #n ")" ::: "memory")

// ---------------------------------------------------------------------------
// f32 -> bf16 cast, 8 elems/thread, grid-stride
// ---------------------------------------------------------------------------
__global__ __launch_bounds__(256)
void cast_bf16_kernel(const float* __restrict__ src, __bf16* __restrict__ dst,
                      long n8) {
  long i = (long)blockIdx.x * blockDim.x + threadIdx.x;
  long stride = (long)gridDim.x * blockDim.x;
  for (; i < n8; i += stride) {
    f32x4 a = ((const f32x4*)src)[2 * i];
    f32x4 b = ((const f32x4*)src)[2 * i + 1];
    bf16x8 w;
    for (int j = 0; j < 4; ++j) { w[j] = (__bf16)a[j]; w[4 + j] = (__bf16)b[j]; }
    ((bf16x8*)dst)[i] = w;
  }
}

// ---------------------------------------------------------------------------
// Transpose + cast: src [K][N] f32 row-major  ->  dst [N][K] bf16 row-major
// ---------------------------------------------------------------------------
__global__ void transpose_cast_kernel(const float* __restrict__ src,
                                      __bf16* __restrict__ dst, int K, int N) {
  __shared__ float tile[32][33];
  int bn = blockIdx.x * 32, bk = blockIdx.y * 32;
  int tx = threadIdx.x, ty = threadIdx.y;  // 32 x 8
  for (int j = 0; j < 32; j += 8)
    tile[ty + j][tx] = src[(size_t)(bk + ty + j) * N + bn + tx];
  __syncthreads();
  for (int j = 0; j < 32; j += 8)
    dst[(size_t)(bn + ty + j) * K + bk + tx] = (__bf16)tile[tx][ty + j];
}

// ---------------------------------------------------------------------------
// gemm_lite: occupancy-first 128x256 MFMA GEMM for GEMM1.
//   C[M][NBt*256] = A[M][KD] @ Bt[NBt*256][KD]^T + bias (relu+bf16 store)
//   512 threads = 8 waves (2 row x 4 col), per-wave output 64x64 (acc = 64
//   VGPR). __launch_bounds__(512, 4) pins regalloc <= 128/wave so 16 waves/CU
//   fit. BK=32, 3-buffer LDS ring (72 KB) -> 2 blocks/CU co-resident; one
//   block's stage/read phases overlap the other's MFMA (m114 mechanism).
//
//   r13 RACE FIX: vmcnt is PER-WAVE, so the counted wait must obey the
//   invariant  wait -> barrier -> read  (as in all verified kernels).
//   r12's "stage; VMCNT; read; barrier" ordering let wave i read LDS rows
//   whose writers (other waves' gload_lds) had not landed -> NaN.
//   Correct per-wave ledger (3 loads per stage call):
//     prologue: stage(0); stage(1); VMCNT(3) [drain st0]; barrier
//               -> slot 0 landed GLOBALLY before any step-0 read.
//     step s:   stage(s+2) [outstanding 6] ; ds_read slot s%3 (safe by
//               the previous barrier) ; MFMA ;
//               VMCNT(3) [drain st(s+1), leave st(s+2)] ; barrier.
//     edges:    s==KT-2: no stage issued -> VMCNT(0); s==KT-1: none.
//   Ring overwrite safety: stage(s+2) targets slot (s-1)%3, whose readers
//   (step s-1 ds_reads) completed before the end-of-step-(s-1) barrier,
//   which precedes this stage issue. One barrier per step.
//   LDS swizzle (BK=32, row=64B, bank cycle 2 rows): slot' = slot ^
//   ((row>>1)&3); pre-swizzled global source -> linear LDS dest
//   [verified 0 SQ_LDS_BANK_CONFLICT in rounds 2/3].
// ---------------------------------------------------------------------------
template <int KD, int NBt, int GRID>
__global__ __launch_bounds__(512, 4)
void gemm_lite(const __bf16* __restrict__ A, const __bf16* __restrict__ Bt,
               const float* __restrict__ bias, __bf16* __restrict__ C) {
  constexpr int KT   = KD / 32;
  constexpr int ABUF = 128 * 32;     // 4096 elems (8 KB)
  constexpr int BBUF = 256 * 32;     // 8192 elems (16 KB)
  constexpr int NDIM = NBt * 256;

  __shared__ __bf16 lA[3 * ABUF];    // 24 KB
  __shared__ __bf16 lB[3 * BBUF];    // 48 KB  (total 72 KB -> 2 blocks/CU)

  constexpr int Q = GRID / 8;        // XCD-bijective swizzle (GRID % 8 == 0)
  int bid = blockIdx.x;
  int swb = (bid & 7) * Q + (bid >> 3);
  const int mb = swb / NBt, nb = swb % NBt;
  const long mrow0 = (long)mb * 128;
  const int  ncol0 = nb * 256;

  const int tid = threadIdx.x;
  const int wid = tid >> 6, lane = tid & 63;
  const int wr = wid >> 2, wc = wid & 3;     // 2 x 4 wave grid
  const int fl = lane & 15, fh = lane >> 4;

  // Fragment LDS element offsets (ring-slot-relative)
  int aoff[4], boff[4];
  #pragma unroll
  for (int mi = 0; mi < 4; ++mi) {
    int row = wr * 64 + mi * 16 + fl;
    aoff[mi] = row * 32 + ((fh ^ ((row >> 1) & 3)) * 8);
  }
  #pragma unroll
  for (int ni = 0; ni < 4; ++ni) {
    int row = wc * 64 + ni * 16 + fl;
    boff[ni] = row * 32 + ((fh ^ ((row >> 1) & 3)) * 8);
  }

  // Staging: thread t covers row r0 = t>>2, 16B slot sl = t&3 (pre-swizzled
  // global source -> linear LDS dest). A: 1 load; B: 2 loads (rows r0, r0+128).
  const int r0 = tid >> 2, sl = tid & 3;
  const long aS  = (mrow0 + r0) * (long)KD + ((sl ^ ((r0 >> 1) & 3)) * 8);
  const long bS0 = ((long)(ncol0 + r0)) * KD + ((sl ^ ((r0 >> 1) & 3)) * 8);
  const long bS1 = ((long)(ncol0 + r0 + 128)) * KD +
                   ((sl ^ (((r0 + 128) >> 1) & 3)) * 8);
  const int dstw = wid * 512;        // wave-uniform chunk (elems, 1 KB/wave)

  auto stage = [&](int t, int bi) {
    gload_lds16(A + aS + (long)t * 32, (void*)(lA + bi * ABUF + dstw));
    gload_lds16(Bt + bS0 + (long)t * 32, (void*)(lB + bi * BBUF + dstw));
    gload_lds16(Bt + bS1 + (long)t * 32, (void*)(lB + bi * BBUF + 4096 + dstw));
  };

  f32x4 acc[4][4] = {};

  // Prologue: stage steps 0 and 1; drain stage 0; barrier -> slot 0 global.
  stage(0, 0);
  stage(1, 1);
  VMCNT(3);
  __builtin_amdgcn_s_barrier();
  __builtin_amdgcn_sched_barrier(0);

  int cur = 0;
  for (int s = 0; s < KT; ++s) {
    const int stg = (cur >= 1) ? cur - 1 : 2;      // (s+2)%3
    if (s + 2 < KT) stage(s + 2, stg);

    // reads of slot cur: landed globally (previous barrier followed a
    // VMCNT that drained stage(s) on every wave)
    bf16x8 af[4], bf[4];
    #pragma unroll
    for (int mi = 0; mi < 4; ++mi)
      af[mi] = *(const bf16x8*)(lA + cur * ABUF + aoff[mi]);
    #pragma unroll
    for (int ni = 0; ni < 4; ++ni)
      bf[ni] = *(const bf16x8*)(lB + cur * BBUF + boff[ni]);

    __builtin_amdgcn_s_setprio(1);
    #pragma unroll
    for (int mi = 0; mi < 4; ++mi)
      #pragma unroll
      for (int ni = 0; ni < 4; ++ni)
        acc[mi][ni] = __builtin_amdgcn_mfma_f32_16x16x32_bf16(
            af[mi], bf[ni], acc[mi][ni], 0, 0, 0);
    __builtin_amdgcn_s_setprio(0);

    // drain stage(s+1) (leave stage(s+2) in flight), THEN barrier:
    // next step's reads are globally safe.
    if (s + 2 < KT)      { VMCNT(3); }
    else if (s + 1 < KT) { VMCNT(0); }   // no stage(s+2) issued
    __builtin_amdgcn_s_barrier();
    __builtin_amdgcn_sched_barrier(0);
    cur = (cur >= 2) ? 0 : cur + 1;
  }

  // Epilogue: bias + relu + bf16 store
  #pragma unroll
  for (int ni = 0; ni < 4; ++ni) {
    int col = ncol0 + wc * 64 + ni * 16 + fl;
    float bv = bias[col];
    #pragma unroll
    for (int mi = 0; mi < 4; ++mi)
      #pragma unroll
      for (int r = 0; r < 4; ++r) {
        long row = mrow0 + wr * 64 + mi * 16 + fh * 4 + r;
        float v = fmaxf(acc[mi][ni][r] + bv, 0.0f);
        C[row * NDIM + col] = (__bf16)v;
      }
  }
}

// ---------------------------------------------------------------------------
// Pipelined-read 8-phase (2*BMH)x256 MFMA GEMM -- r10-verified, used for GEMM2.
// ---------------------------------------------------------------------------
template <int KD, int BMH, int NBt, bool RELU_OUT, bool LNFUSE, int GRID>
__global__ __launch_bounds__(512)
void gemm_8ph(const __bf16* __restrict__ A, const __bf16* __restrict__ Bt,
              const float* __restrict__ bias,
              const float* __restrict__ lng, const float* __restrict__ lnb,
              void* __restrict__ Cv) {
  static_assert(!LNFUSE || NBt == 1, "LN fusion needs full rows per block");
  constexpr int KT    = KD / 64;
  constexpr int MI    = BMH / 32;
  constexpr int AHALF = BMH * 64;
  constexpr int BHALF = 128 * 64;
  constexpr int ASTEP = 2 * AHALF;
  constexpr int BSTEP = 2 * BHALF;
  constexpr int NDIM  = NBt * 256;
  constexpr int AUL   = BMH / 64;

  __shared__ __bf16 lA[2 * ASTEP];
  __shared__ __bf16 lB[2 * BSTEP];

  constexpr int Q = GRID / 8;
  int bid = blockIdx.x;
  int swb = (bid & 7) * Q + (bid >> 3);
  const int mb = swb / NBt, nb = swb % NBt;
  const long mrow0 = (long)mb * (2 * BMH);
  const int  ncol0 = nb * 256;

  const int tid = threadIdx.x;
  const int wid = tid >> 6, lane = tid & 63;
  const int wr = wid >> 2, wc = wid & 3;
  const int fl = lane & 15, fh = lane >> 4;

  int aoff[MI][2], boff[2][2];
  #pragma unroll
  for (int mi = 0; mi < MI; ++mi)
    #pragma unroll
    for (int ks = 0; ks < 2; ++ks) {
      int row = wr * (BMH / 2) + mi * 16 + fl;
      aoff[mi][ks] = row * 64 + (((ks * 4 + fh) ^ (row & 7)) * 8);
    }
  #pragma unroll
  for (int ni = 0; ni < 2; ++ni)
    #pragma unroll
    for (int ks = 0; ks < 2; ++ks) {
      int row = wc * 32 + ni * 16 + fl;
      boff[ni][ks] = row * 64 + (((ks * 4 + fh) ^ (row & 7)) * 8);
    }

  const int r0 = tid >> 3, sl = tid & 7;
  long aS[2][AUL], bS[2][2];
  #pragma unroll
  for (int h = 0; h < 2; ++h) {
    #pragma unroll
    for (int i = 0; i < AUL; ++i) {
      int rr = r0 + i * 64;
      int ss = sl ^ (rr & 7);
      aS[h][i] = (mrow0 + h * BMH + rr) * (long)KD + ss * 8;
    }
    #pragma unroll
    for (int i = 0; i < 2; ++i) {
      int rr = r0 + i * 64;
      int ss = sl ^ (rr & 7);
      bS[h][i] = ((long)(ncol0 + h * 128 + rr)) * KD + ss * 8;
    }
  }
  const int dstw = wid * 512;

  auto stA = [&](int h, int t) {
    __bf16* base = lA + (t & 1) * ASTEP + h * AHALF + dstw;
    #pragma unroll
    for (int i = 0; i < AUL; ++i)
      gload_lds16(A + aS[h][i] + (long)t * 64, (void*)(base + i * 4096));
  };
  auto stB = [&](int h, int t) {
    __bf16* base = lB + (t & 1) * BSTEP + h * BHALF + dstw;
    #pragma unroll
    for (int i = 0; i < 2; ++i)
      gload_lds16(Bt + bS[h][i] + (long)t * 64, (void*)(base + i * 4096));
  };

  bf16x8 aregA[MI][2], aregB[MI][2], breg0[2][2], breg1[2][2];
  auto loadA = [&](bf16x8 (&ar)[MI][2], int mh, int s) {
    const __bf16* base = lA + (s & 1) * ASTEP + mh * AHALF;
    #pragma unroll
    for (int mi = 0; mi < MI; ++mi)
      #pragma unroll
      for (int ks = 0; ks < 2; ++ks)
        ar[mi][ks] = *(const bf16x8*)(base + aoff[mi][ks]);
  };
  auto loadB = [&](bf16x8 (&br)[2][2], int nh, int s) {
    const __bf16* base = lB + (s & 1) * BSTEP + nh * BHALF;
    #pragma unroll
    for (int ni = 0; ni < 2; ++ni)
      #pragma unroll
      for (int ks = 0; ks < 2; ++ks)
        br[ni][ks] = *(const bf16x8*)(base + boff[ni][ks]);
  };

  f32x4 acc[2][2][MI][2] = {};

#define PHASE_MFMA(mh, nh, AR, BR)                                            \
  __builtin_amdgcn_s_setprio(1);                                              \
  _Pragma("unroll")                                                           \
  for (int ks = 0; ks < 2; ++ks) {                                            \
    _Pragma("unroll")                                                         \
    for (int mi = 0; mi < MI; ++mi) {                                         \
      _Pragma("unroll")                                                       \
      for (int ni = 0; ni < 2; ++ni)                                          \
        acc[mh][nh][mi][ni] = __builtin_amdgcn_mfma_f32_16x16x32_bf16(        \
            AR[mi][ks], BR[ni][ks], acc[mh][nh][mi][ni], 0, 0, 0);            \
    }                                                                         \
  }                                                                           \
  __builtin_amdgcn_s_setprio(0);

  stA(0, 0); stB(0, 0); stA(1, 0); stB(1, 0);
  stA(0, 1); stB(1, 1); stB(0, 1); stA(1, 1);
  if constexpr (AUL == 2) { VMCNT(8); } else { VMCNT(6); }
  __builtin_amdgcn_s_barrier();
  __builtin_amdgcn_sched_barrier(0);
  loadA(aregA, 0, 0);
  loadB(breg0, 0, 0);

  for (int s = 0; s < KT; ++s) {
    if (s >= 1 && s + 1 < KT) stB(0, s + 1);
    loadB(breg1, 1, s);
    PHASE_MFMA(0, 0, aregA, breg0);
    if (s + 1 < KT) {
      if constexpr (AUL == 2) { VMCNT(6); } else { VMCNT(5); }
    } else {
      VMCNT(0);
    }
    __builtin_amdgcn_s_barrier();
    __builtin_amdgcn_sched_barrier(0);

    if (s >= 1 && s + 1 < KT) stA(1, s + 1);
    loadA(aregB, 1, s);
    PHASE_MFMA(0, 1, aregA, breg1);
    __builtin_amdgcn_s_barrier();
    __builtin_amdgcn_sched_barrier(0);

    if (s + 2 < KT) stA(0, s + 2);
    PHASE_MFMA(1, 1, aregB, breg1);
    if (s + 2 < KT) {
      if constexpr (AUL == 2) { VMCNT(4); } else { VMCNT(2); }
    } else if (s + 1 < KT) {
      if constexpr (AUL == 2) { VMCNT(2); } else { VMCNT(1); }
    } else {
      VMCNT(0);
    }
    __builtin_amdgcn_s_barrier();
    __builtin_amdgcn_sched_barrier(0);

    if (s + 2 < KT) stB(1, s + 2);
    PHASE_MFMA(1, 0, aregB, breg0);
    if (s + 1 < KT) {
      loadA(aregA, 0, s + 1);
      loadB(breg0, 0, s + 1);
    }
    __builtin_amdgcn_s_barrier();
    __builtin_amdgcn_sched_barrier(0);
  }

#undef PHASE_MFMA

  if constexpr (LNFUSE) {
    float (*s1p)[4] = (float(*)[4])((float*)lA);
    float (*s2p)[4] = (float(*)[4])((float*)lA + 512);
    float (*n2p)[4] = (float(*)[4])((float*)lA + 1024);

    float v[2][2][MI][2][4];
    float gg[2][2], bb[2][2];
    #pragma unroll
    for (int nh = 0; nh < 2; ++nh)
      #pragma unroll
      for (int ni = 0; ni < 2; ++ni) {
        int c = nh * 128 + wc * 32 + ni * 16 + fl;
        float bv = bias[c];
        gg[nh][ni] = lng[c]; bb[nh][ni] = lnb[c];
        #pragma unroll
        for (int mh = 0; mh < 2; ++mh)
          #pragma unroll
          for (int mi = 0; mi < MI; ++mi)
            #pragma unroll
            for (int r = 0; r < 4; ++r)
              v[mh][nh][mi][ni][r] = acc[mh][nh][mi][ni][r] + bv;
      }

    #pragma unroll
    for (int mh = 0; mh < 2; ++mh)
      #pragma unroll
      for (int mi = 0; mi < MI; ++mi)
        #pragma unroll
        for (int r = 0; r < 4; ++r) {
          float s1 = 0.0f, s2 = 0.0f;
          #pragma unroll
          for (int nh = 0; nh < 2; ++nh)
            #pragma unroll
            for (int ni = 0; ni < 2; ++ni) {
              float x = v[mh][nh][mi][ni][r];
              s1 += x; s2 += x * x;
            }
          for (int m = 1; m < 16; m <<= 1) {
            s1 += __shfl_xor(s1, m, 64);
            s2 += __shfl_xor(s2, m, 64);
          }
          if (fl == 0) {
            int lr = mh * 64 + wr * 32 + mi * 16 + fh * 4 + r;
            s1p[lr][wc] = s1; s2p[lr][wc] = s2;
          }
        }
    __syncthreads();

    float n2loc[2][MI][4];
    #pragma unroll
    for (int mh = 0; mh < 2; ++mh)
      #pragma unroll
      for (int mi = 0; mi < MI; ++mi)
        #pragma unroll
        for (int r = 0; r < 4; ++r) {
          int lr = mh * 64 + wr * 32 + mi * 16 + fh * 4 + r;
          float t1 = s1p[lr][0] + s1p[lr][1] + s1p[lr][2] + s1p[lr][3];
          float t2 = s2p[lr][0] + s2p[lr][1] + s2p[lr][2] + s2p[lr][3];
          float mu = t1 * (1.0f / PDIM);
          float var = t2 * (1.0f / PDIM) - mu * mu;
          float rstd = rsqrtf(var + 1e-5f);
          float n2 = 0.0f;
          #pragma unroll
          for (int nh = 0; nh < 2; ++nh)
            #pragma unroll
            for (int ni = 0; ni < 2; ++ni) {
              float y = (v[mh][nh][mi][ni][r] - mu) * rstd * gg[nh][ni] + bb[nh][ni];
              v[mh][nh][mi][ni][r] = y;
              n2 += y * y;
            }
          for (int m = 1; m < 16; m <<= 1) n2 += __shfl_xor(n2, m, 64);
          n2loc[mh][mi][r] = n2;
        }
    #pragma unroll
    for (int mh = 0; mh < 2; ++mh)
      #pragma unroll
      for (int mi = 0; mi < MI; ++mi)
        #pragma unroll
        for (int r = 0; r < 4; ++r)
          if (fl == 0) {
            int lr = mh * 64 + wr * 32 + mi * 16 + fh * 4 + r;
            n2p[lr][wc] = n2loc[mh][mi][r];
          }
    __syncthreads();

    #pragma unroll
    for (int mh = 0; mh < 2; ++mh)
      #pragma unroll
      for (int mi = 0; mi < MI; ++mi)
        #pragma unroll
        for (int r = 0; r < 4; ++r) {
          int lr = mh * 64 + wr * 32 + mi * 16 + fh * 4 + r;
          float t = n2p[lr][0] + n2p[lr][1] + n2p[lr][2] + n2p[lr][3];
          float sc = 1.0f / fmaxf(sqrtf(t), 1e-12f);
          #pragma unroll
          for (int nh = 0; nh < 2; ++nh)
            #pragma unroll
            for (int ni = 0; ni < 2; ++ni) {
              int c = nh * 128 + wc * 32 + ni * 16 + fl;
              ((float*)Cv)[(mrow0 + lr) * NDIM + c] = v[mh][nh][mi][ni][r] * sc;
            }
        }
  } else {
    #pragma unroll
    for (int mh = 0; mh < 2; ++mh)
      #pragma unroll
      for (int nh = 0; nh < 2; ++nh)
        #pragma unroll
        for (int ni = 0; ni < 2; ++ni) {
          int col = ncol0 + nh * 128 + wc * 32 + ni * 16 + fl;
          float bv = bias[col];
          #pragma unroll
          for (int mi = 0; mi < MI; ++mi)
            #pragma unroll
            for (int r = 0; r < 4; ++r) {
              long row = mrow0 + mh * BMH + wr * (BMH / 2) + mi * 16 + fh * 4 + r;
              float x = acc[mh][nh][mi][ni][r] + bv;
              if constexpr (RELU_OUT) {
                x = fmaxf(x, 0.0f);
                ((__bf16*)Cv)[row * NDIM + col] = (__bf16)x;
              } else {
                ((float*)Cv)[row * NDIM + col] = x;
              }
            }
        }
  }
}

// ---------------------------------------------------------------------------
// Per-row contrastive loss. One wave per row; 16-lane groups handle 4 negs
// at a time; negatives read as bf16 (halves L2 gather traffic).
// ---------------------------------------------------------------------------
__global__ __launch_bounds__(256)
void loss_kernel(const float* __restrict__ X, const __bf16* __restrict__ negb,
                 const int* __restrict__ nidx, float* __restrict__ partials) {
  __shared__ float lsum[4];
  int b    = blockIdx.x * 4 + (threadIdx.x >> 6);
  int lane = threadIdx.x & 63;
  int g = lane >> 4, lg = lane & 15;

  const float* arow = X + (size_t)b * PDIM;
  const float* prow = X + (size_t)(BATCH + b) * PDIM;

  float a16[16];
  #pragma unroll
  for (int j = 0; j < 4; ++j) {
    f32x4 av = *(const f32x4*)(arow + lg * 16 + j * 4);
    #pragma unroll
    for (int e = 0; e < 4; ++e) a16[j * 4 + e] = av[e];
  }

  float ps = 0.0f;
  #pragma unroll
  for (int j = 0; j < 4; ++j) {
    f32x4 p = *(const f32x4*)(prow + lg * 16 + j * 4);
    #pragma unroll
    for (int e = 0; e < 4; ++e) ps += a16[j * 4 + e] * p[e];
  }
  for (int m = 1; m < 16; m <<= 1) ps += __shfl_xor(ps, m, 64);
  float pos = ps * 2.0f;  // /TEMPERATURE

  float myneg = -3.0e38f;
  for (int k4 = 0; k4 < 16; ++k4) {
    int k = k4 * 4 + g;
    int idx = nidx[(size_t)b * KNEG + k];
    const __bf16* nrow = negb + (size_t)idx * PDIM;
    float sv = 0.0f;
    #pragma unroll
    for (int j = 0; j < 2; ++j) {
      bf16x8 nv = *(const bf16x8*)(nrow + lg * 16 + j * 8);
      #pragma unroll
      for (int e = 0; e < 8; ++e) sv += a16[j * 8 + e] * (float)nv[e];
    }
    for (int m = 1; m < 16; m <<= 1) sv += __shfl_xor(sv, m, 64);
    if (lg == k4) myneg = sv * 2.0f;
  }

  float mx = myneg;
  for (int m = 1; m < 64; m <<= 1) mx = fmaxf(mx, __shfl_xor(mx, m, 64));
  mx = fmaxf(mx, pos);
  float e = expf(myneg - mx);
  for (int m = 1; m < 64; m <<= 1) e += __shfl_xor(e, m, 64);
  float tot = e + expf(pos - mx);
  float lb = -(pos - mx - logf(tot));

  if (lane == 0) lsum[threadIdx.x >> 6] = lb;
  __syncthreads();
  if (threadIdx.x == 0)
    partials[blockIdx.x] = lsum[0] + lsum[1] + lsum[2] + lsum[3];
}

__global__ void finalize_kernel(const float* __restrict__ partials,
                                float* __restrict__ out) {
  __shared__ float ls[4];
  int tid = threadIdx.x;
  float s = 0.0f;
  for (int i = tid; i < 4096; i += 256) s += partials[i];
  for (int m = 1; m < 64; m <<= 1) s += __shfl_xor(s, m, 64);
  if ((tid & 63) == 0) ls[tid >> 6] = s;
  __syncthreads();
  if (tid == 0) out[0] = (ls[0] + ls[1] + ls[2] + ls[3]) * (1.0f / BATCH);
}

// ---------------------------------------------------------------------------
extern "C" void kernel_launch(void* const* d_in, const int* in_sizes, int n_in,
                              void* d_out, int out_size, void* d_ws, size_t ws_size,
                              hipStream_t stream) {
  const float* hidden   = (const float*)d_in[0];
  const float* positive = (const float*)d_in[1];
  const float* negbuf   = (const float*)d_in[2];
  const float* W1       = (const float*)d_in[3];
  const float* b1       = (const float*)d_in[4];
  const float* W2       = (const float*)d_in[5];
  const float* b2       = (const float*)d_in[6];
  const float* gamma    = (const float*)d_in[7];
  const float* beta     = (const float*)d_in[8];
  const int*   nidx     = (const int*)d_in[9];
  float* out = (float*)d_out;

  char* ws = (char*)d_ws;
  // Layout (~204 MiB; ws proven >= 206 MiB in rounds 2-10):
  const size_t OFF_Y1   = 134217728;
  const size_t OFF_W1T  = OFF_Y1 + 67108864;
  const size_t OFF_W2T  = OFF_W1T + 4194304;
  const size_t OFF_NEGB = OFF_W2T + 524288;
  const size_t OFF_PART = OFF_NEGB + 1048576;

  __bf16* Abf      = (__bf16*)(ws);
  __bf16* Y1       = (__bf16*)(ws + OFF_Y1);
  __bf16* W1T      = (__bf16*)(ws + OFF_W1T);
  __bf16* W2T      = (__bf16*)(ws + OFF_W2T);
  __bf16* negb     = (__bf16*)(ws + OFF_NEGB);
  float*  partials = (float*) (ws + OFF_PART);
  float*  X        = (float*) (ws);  // overlaps dead Abf

  transpose_cast_kernel<<<dim3(HHDIM / 32, HDIM / 32), dim3(32, 8), 0, stream>>>(
      W1, W1T, HDIM, HHDIM);
  transpose_cast_kernel<<<dim3(PDIM / 32, HHDIM / 32), dim3(32, 8), 0, stream>>>(
      W2, W2T, HHDIM, PDIM);

  const long n8 = (long)BATCH * HDIM / 8;
  cast_bf16_kernel<<<2048, 256, 0, stream>>>(hidden, Abf, n8);
  cast_bf16_kernel<<<2048, 256, 0, stream>>>(positive, Abf + (size_t)BATCH * HDIM, n8);
  cast_bf16_kernel<<<256, 256, 0, stream>>>(negbuf, negb, (long)NBUF * PDIM / 8);

  // GEMM1: Abf @ W1T^T + b1, relu -> Y1 (bf16).
  // 128x256 tile, 72KB LDS, <=128 regs/wave -> 2 blocks/CU (16 waves).
  gemm_lite<HDIM, HHDIM / 256, (M1 / 128) * (HHDIM / 256)>
      <<<(M1 / 128) * (HHDIM / 256), 512, 0, stream>>>(Abf, W1T, b1, Y1);

  // GEMM2: Y1 @ W2T^T + b2, fused LayerNorm + L2-normalize -> X (f32).
  gemm_8ph<HHDIM, 64, PDIM / 256, false, true, (M1 / 128) * (PDIM / 256)>
      <<<(M1 / 128) * (PDIM / 256), 512, 0, stream>>>(
          Y1, W2T, b2, gamma, beta, X);

  loss_kernel<<<BATCH / 4, 256, 0, stream>>>(X, negb, nidx, partials);
  finalize_kernel<<<1, 256, 0, stream>>>(partials, out);
}

// Round 15
// 308.087 us; speedup vs baseline: 1.0606x; 1.0606x over previous
//
#include <hip/hip_runtime.h>
#include <hip/hip_bf16.h>
#include <cstdint>

// Problem constants
#define BATCH   16384
#define HDIM    2048
#define HHDIM   1024
#define PDIM    256
#define KNEG    64
#define NBUF    2000
#define M1      (2 * BATCH)          // 32768 rows through the projection head

typedef float  f32x4  __attribute__((ext_vector_type(4)));
typedef __bf16 bf16x8 __attribute__((ext_vector_type(8)));

typedef __attribute__((address_space(3))) unsigned int       lds_u32;
typedef __attribute__((address_space(1))) const unsigned int glb_u32;

__device__ __forceinline__ void gload_lds16(const void* g, void* l) {
  __builtin_amdgcn_global_load_lds((glb_u32*)g, (lds_u32*)l, 16, 0, 0);
}

#define VMCNT(n) asm volatile("s_waitcnt vmcnt(" #n ")" ::: "memory")
#define LGKM(n)  asm volatile("s_waitcnt lgkmcnt(" #n ")" ::: "memory")

// ---------------------------------------------------------------------------
// f32 -> bf16 cast, 8 elems/thread, grid-stride (used only for neg_buffer)
// ---------------------------------------------------------------------------
__global__ __launch_bounds__(256)
void cast_bf16_kernel(const float* __restrict__ src, __bf16* __restrict__ dst,
                      long n8) {
  long i = (long)blockIdx.x * blockDim.x + threadIdx.x;
  long stride = (long)gridDim.x * blockDim.x;
  for (; i < n8; i += stride) {
    f32x4 a = ((const f32x4*)src)[2 * i];
    f32x4 b = ((const f32x4*)src)[2 * i + 1];
    bf16x8 w;
    for (int j = 0; j < 4; ++j) { w[j] = (__bf16)a[j]; w[4 + j] = (__bf16)b[j]; }
    ((bf16x8*)dst)[i] = w;
  }
}

// ---------------------------------------------------------------------------
// Transpose + cast: src [K][N] f32 row-major  ->  dst [N][K] bf16 row-major
// ---------------------------------------------------------------------------
__global__ void transpose_cast_kernel(const float* __restrict__ src,
                                      __bf16* __restrict__ dst, int K, int N) {
  __shared__ float tile[32][33];
  int bn = blockIdx.x * 32, bk = blockIdx.y * 32;
  int tx = threadIdx.x, ty = threadIdx.y;  // 32 x 8
  for (int j = 0; j < 32; j += 8)
    tile[ty + j][tx] = src[(size_t)(bk + ty + j) * N + bn + tx];
  __syncthreads();
  for (int j = 0; j < 32; j += 8)
    dst[(size_t)(bn + ty + j) * K + bk + tx] = (__bf16)tile[tx][ty + j];
}

// ---------------------------------------------------------------------------
// gemm_f32a: 256x256 MFMA GEMM with fp32 A staged RAW into LDS (cast-free).
//   C = A(f32)[M][KD] @ Bt(bf16)[NBt*256][KD]^T + bias, relu, bf16 store.
//   Eliminates the 2 x 134MB A-cast kernels: gload_lds stages f32 bytes
//   unchanged; conversion f32->bf16 happens AFTER ds_read, before MFMA
//   (no mid-phase vmcnt drain -- r7's failure mode avoided; prefetch
//   distance stays one full K-step).
//   512 threads = 8 waves (2x4). BK=32, KT=64. LDS 96 KB:
//     lAf f32 [2 buf][2 half][128x32]  (64 KB), row=128B=8 slots,
//         swizzle slot^(row&7)           [verified rounds 5-10]
//     lBf bf16 [2 buf][2 half][128x32] (32 KB), row=64B=4 slots,
//         swizzle slot^((row>>1)&3)      [verified rounds 2/3/14]
//   Phases per step s (r6-verified skeleton):
//     p1 Q(0,0): ds_read A0 raw(8xf32x4)+B0(2); stage B0(s+1)[1]
//     p2 Q(0,1): ds_read B1(2);                 stage A1(s+1)[2]
//     p3 Q(1,1): ds_read A1 raw;                stage A0(s+2)[2]
//     p4 Q(1,0): no reads;                      stage B1(s+2)[1]
//   vmcnt ledger (stA=2, stB=1 loads): prologue stages steps 0+1 (12
//   loads), VMCNT(6) leaves step-1's 6 -> step 0 landed. End-p4(s):
//   outstanding = carryover {A0(s+1),B1(s+1)}(3) + this step's 6 = 9;
//   VMCNT(3) leaves {A0(s+2),B1(s+2)} -> ALL of step s+1 landed.
//   Edges: s+2>=KT -> fewer issued -> VMCNT(0) (covers s=KT-2, KT-1).
//   Overwrite safety: each stage target's readers drained (LGKM(0)
//   before MFMA) >=2 barriers before the stage issue.
//   Bank check (A f32 frag reads): row stride 128B = exact bank cycle;
//   64 lanes spread over 8 slots x 8 lanes = 2 lanes/bank -> free.
// ---------------------------------------------------------------------------
template <int KD, int NBt, int GRID>
__global__ __launch_bounds__(512)
void gemm_f32a(const float* __restrict__ A0, const float* __restrict__ A1v,
               const __bf16* __restrict__ Bt, const float* __restrict__ bias,
               __bf16* __restrict__ C) {
  constexpr int KT   = KD / 32;
  constexpr int NDIM = NBt * 256;

  __shared__ float  lAf[2 * 2 * 4096];   // 64 KB
  __shared__ __bf16 lBf[2 * 2 * 4096];   // 32 KB

  constexpr int Q = GRID / 8;            // XCD-bijective swizzle (GRID%8==0)
  int bid = blockIdx.x;
  int swb = (bid & 7) * Q + (bid >> 3);
  const int mb = swb / NBt, nb = swb % NBt;
  const long mrow0 = (long)mb * 256;
  const int  ncol0 = nb * 256;

  // block rows entirely within one input (256 | BATCH)
  const float* Af = (mrow0 < BATCH) ? (A0 + mrow0 * (long)KD)
                                    : (A1v + (mrow0 - BATCH) * (long)KD);

  const int tid = threadIdx.x;
  const int wid = tid >> 6, lane = tid & 63;
  const int wr = wid >> 2, wc = wid & 3;   // 2 x 4 wave grid
  const int fl = lane & 15, fh = lane >> 4;

  // A fragment read offsets (f32 elems, half-relative): frag = 16 rows x 32K,
  // lane (fl,fh) holds K fh*8..fh*8+7 = slots {2fh, 2fh+1} of row.
  int aoffs[4][2];
  #pragma unroll
  for (int mi = 0; mi < 4; ++mi)
    #pragma unroll
    for (int p = 0; p < 2; ++p) {
      int row = wr * 64 + mi * 16 + fl;
      aoffs[mi][p] = row * 32 + (((2 * fh + p) ^ (row & 7)) * 4);
    }
  // B fragment read offsets (bf16 elems, half-relative)
  int boffs[2];
  #pragma unroll
  for (int ni = 0; ni < 2; ++ni) {
    int row = wc * 32 + ni * 16 + fl;
    boffs[ni] = row * 32 + ((fh ^ ((row >> 1) & 3)) * 8);
  }

  // Staging (pre-swizzled global source -> linear LDS dest)
  const int r0a = tid >> 3, ssa = (tid & 7) ^ ((tid >> 3) & 7);
  const int r0b = tid >> 2, ssb = (tid & 3) ^ (((tid >> 2) >> 1) & 3);
  const int dwA = wid * 256;   // f32 elems (wave-uniform 1 KB chunk)
  const int dwB = wid * 512;   // bf16 elems

  auto stA = [&](int h, int t) {   // 2 loads (rows r0a, r0a+64; same swz)
    float* base = lAf + (t & 1) * 8192 + h * 4096 + dwA;
    const float* s0 = Af + (size_t)(h * 128 + r0a) * KD + t * 32 + ssa * 4;
    gload_lds16(s0, (void*)base);
    gload_lds16(s0 + (size_t)64 * KD, (void*)(base + 2048));
  };
  auto stB = [&](int h, int t) {   // 1 load
    __bf16* base = lBf + (t & 1) * 8192 + h * 4096 + dwB;
    gload_lds16(Bt + (size_t)(ncol0 + h * 128 + r0b) * KD + t * 32 + ssb * 8,
                (void*)base);
  };

  f32x4  aA[4][2];                 // raw f32 A fragments
  bf16x8 areg[4], breg0[2], breg1[2];

  auto loadAraw = [&](int mh, int s) {
    const float* base = lAf + (s & 1) * 8192 + mh * 4096;
    #pragma unroll
    for (int mi = 0; mi < 4; ++mi)
      #pragma unroll
      for (int p = 0; p < 2; ++p)
        aA[mi][p] = *(const f32x4*)(base + aoffs[mi][p]);
  };
  auto cvtA = [&]() {
    #pragma unroll
    for (int mi = 0; mi < 4; ++mi)
      #pragma unroll
      for (int j = 0; j < 4; ++j) {
        areg[mi][j]     = (__bf16)aA[mi][0][j];
        areg[mi][4 + j] = (__bf16)aA[mi][1][j];
      }
  };
  auto loadB = [&](bf16x8 (&br)[2], int nh, int s) {
    const __bf16* base = lBf + (s & 1) * 8192 + nh * 4096;
    #pragma unroll
    for (int ni = 0; ni < 2; ++ni)
      br[ni] = *(const bf16x8*)(base + boffs[ni]);
  };

  f32x4 acc[2][2][4][2] = {};

#define QMFMA(mh, nh, BR)                                                     \
  __builtin_amdgcn_s_setprio(1);                                              \
  _Pragma("unroll")                                                           \
  for (int mi = 0; mi < 4; ++mi) {                                            \
    _Pragma("unroll")                                                         \
    for (int ni = 0; ni < 2; ++ni)                                            \
      acc[mh][nh][mi][ni] = __builtin_amdgcn_mfma_f32_16x16x32_bf16(          \
          areg[mi], BR[ni], acc[mh][nh][mi][ni], 0, 0, 0);                    \
  }                                                                           \
  __builtin_amdgcn_s_setprio(0);

  // Prologue: stage steps 0 and 1 (12 loads); leave step-1's 6 in flight.
  stA(0, 0); stB(0, 0); stA(1, 0); stB(1, 0);
  stA(0, 1); stB(1, 1); stB(0, 1); stA(1, 1);
  VMCNT(6);
  __builtin_amdgcn_s_barrier();
  __builtin_amdgcn_sched_barrier(0);

  for (int s = 0; s < KT; ++s) {
    // ---- p1: Q(0,0)
    loadAraw(0, s);
    loadB(breg0, 0, s);
    if (s >= 1 && s + 1 < KT) stB(0, s + 1);
    __builtin_amdgcn_s_barrier();
    LGKM(0);
    __builtin_amdgcn_sched_barrier(0);
    cvtA();
    QMFMA(0, 0, breg0);
    __builtin_amdgcn_s_barrier();

    // ---- p2: Q(0,1)
    loadB(breg1, 1, s);
    if (s >= 1 && s + 1 < KT) stA(1, s + 1);
    __builtin_amdgcn_s_barrier();
    LGKM(0);
    __builtin_amdgcn_sched_barrier(0);
    QMFMA(0, 1, breg1);
    __builtin_amdgcn_s_barrier();

    // ---- p3: Q(1,1)
    loadAraw(1, s);
    if (s + 2 < KT) stA(0, s + 2);
    __builtin_amdgcn_s_barrier();
    LGKM(0);
    __builtin_amdgcn_sched_barrier(0);
    cvtA();
    QMFMA(1, 1, breg1);
    __builtin_amdgcn_s_barrier();

    // ---- p4: Q(1,0) (no reads; breg0/areg held)
    if (s + 2 < KT) stB(1, s + 2);
    __builtin_amdgcn_s_barrier();
    __builtin_amdgcn_sched_barrier(0);
    QMFMA(1, 0, breg0);
    if (s + 2 < KT) { VMCNT(3); } else { VMCNT(0); }
    __builtin_amdgcn_s_barrier();
    __builtin_amdgcn_sched_barrier(0);
  }

#undef QMFMA

  // Epilogue: bias + relu + bf16 store
  #pragma unroll
  for (int mh = 0; mh < 2; ++mh)
    #pragma unroll
    for (int nh = 0; nh < 2; ++nh)
      #pragma unroll
      for (int ni = 0; ni < 2; ++ni) {
        int col = ncol0 + nh * 128 + wc * 32 + ni * 16 + fl;
        float bv = bias[col];
        #pragma unroll
        for (int mi = 0; mi < 4; ++mi)
          #pragma unroll
          for (int r = 0; r < 4; ++r) {
            long row = mrow0 + mh * 128 + wr * 64 + mi * 16 + fh * 4 + r;
            float v = fmaxf(acc[mh][nh][mi][ni][r] + bv, 0.0f);
            C[row * NDIM + col] = (__bf16)v;
          }
      }
}

// ---------------------------------------------------------------------------
// Pipelined-read 8-phase (2*BMH)x256 MFMA GEMM -- r10-verified, used for GEMM2.
// ---------------------------------------------------------------------------
template <int KD, int BMH, int NBt, bool RELU_OUT, bool LNFUSE, int GRID>
__global__ __launch_bounds__(512)
void gemm_8ph(const __bf16* __restrict__ A, const __bf16* __restrict__ Bt,
              const float* __restrict__ bias,
              const float* __restrict__ lng, const float* __restrict__ lnb,
              void* __restrict__ Cv) {
  static_assert(!LNFUSE || NBt == 1, "LN fusion needs full rows per block");
  constexpr int KT    = KD / 64;
  constexpr int MI    = BMH / 32;
  constexpr int AHALF = BMH * 64;
  constexpr int BHALF = 128 * 64;
  constexpr int ASTEP = 2 * AHALF;
  constexpr int BSTEP = 2 * BHALF;
  constexpr int NDIM  = NBt * 256;
  constexpr int AUL   = BMH / 64;

  __shared__ __bf16 lA[2 * ASTEP];
  __shared__ __bf16 lB[2 * BSTEP];

  constexpr int Q = GRID / 8;
  int bid = blockIdx.x;
  int swb = (bid & 7) * Q + (bid >> 3);
  const int mb = swb / NBt, nb = swb % NBt;
  const long mrow0 = (long)mb * (2 * BMH);
  const int  ncol0 = nb * 256;

  const int tid = threadIdx.x;
  const int wid = tid >> 6, lane = tid & 63;
  const int wr = wid >> 2, wc = wid & 3;
  const int fl = lane & 15, fh = lane >> 4;

  int aoff[MI][2], boff[2][2];
  #pragma unroll
  for (int mi = 0; mi < MI; ++mi)
    #pragma unroll
    for (int ks = 0; ks < 2; ++ks) {
      int row = wr * (BMH / 2) + mi * 16 + fl;
      aoff[mi][ks] = row * 64 + (((ks * 4 + fh) ^ (row & 7)) * 8);
    }
  #pragma unroll
  for (int ni = 0; ni < 2; ++ni)
    #pragma unroll
    for (int ks = 0; ks < 2; ++ks) {
      int row = wc * 32 + ni * 16 + fl;
      boff[ni][ks] = row * 64 + (((ks * 4 + fh) ^ (row & 7)) * 8);
    }

  const int r0 = tid >> 3, sl = tid & 7;
  long aS[2][AUL], bS[2][2];
  #pragma unroll
  for (int h = 0; h < 2; ++h) {
    #pragma unroll
    for (int i = 0; i < AUL; ++i) {
      int rr = r0 + i * 64;
      int ss = sl ^ (rr & 7);
      aS[h][i] = (mrow0 + h * BMH + rr) * (long)KD + ss * 8;
    }
    #pragma unroll
    for (int i = 0; i < 2; ++i) {
      int rr = r0 + i * 64;
      int ss = sl ^ (rr & 7);
      bS[h][i] = ((long)(ncol0 + h * 128 + rr)) * KD + ss * 8;
    }
  }
  const int dstw = wid * 512;

  auto stA = [&](int h, int t) {
    __bf16* base = lA + (t & 1) * ASTEP + h * AHALF + dstw;
    #pragma unroll
    for (int i = 0; i < AUL; ++i)
      gload_lds16(A + aS[h][i] + (long)t * 64, (void*)(base + i * 4096));
  };
  auto stB = [&](int h, int t) {
    __bf16* base = lB + (t & 1) * BSTEP + h * BHALF + dstw;
    #pragma unroll
    for (int i = 0; i < 2; ++i)
      gload_lds16(Bt + bS[h][i] + (long)t * 64, (void*)(base + i * 4096));
  };

  bf16x8 aregA[MI][2], aregB[MI][2], breg0[2][2], breg1[2][2];
  auto loadA = [&](bf16x8 (&ar)[MI][2], int mh, int s) {
    const __bf16* base = lA + (s & 1) * ASTEP + mh * AHALF;
    #pragma unroll
    for (int mi = 0; mi < MI; ++mi)
      #pragma unroll
      for (int ks = 0; ks < 2; ++ks)
        ar[mi][ks] = *(const bf16x8*)(base + aoff[mi][ks]);
  };
  auto loadB = [&](bf16x8 (&br)[2][2], int nh, int s) {
    const __bf16* base = lB + (s & 1) * BSTEP + nh * BHALF;
    #pragma unroll
    for (int ni = 0; ni < 2; ++ni)
      #pragma unroll
      for (int ks = 0; ks < 2; ++ks)
        br[ni][ks] = *(const bf16x8*)(base + boff[ni][ks]);
  };

  f32x4 acc[2][2][MI][2] = {};

#define PHASE_MFMA(mh, nh, AR, BR)                                            \
  __builtin_amdgcn_s_setprio(1);                                              \
  _Pragma("unroll")                                                           \
  for (int ks = 0; ks < 2; ++ks) {                                            \
    _Pragma("unroll")                                                         \
    for (int mi = 0; mi < MI; ++mi) {                                         \
      _Pragma("unroll")                                                       \
      for (int ni = 0; ni < 2; ++ni)                                          \
        acc[mh][nh][mi][ni] = __builtin_amdgcn_mfma_f32_16x16x32_bf16(        \
            AR[mi][ks], BR[ni][ks], acc[mh][nh][mi][ni], 0, 0, 0);            \
    }                                                                         \
  }                                                                           \
  __builtin_amdgcn_s_setprio(0);

  stA(0, 0); stB(0, 0); stA(1, 0); stB(1, 0);
  stA(0, 1); stB(1, 1); stB(0, 1); stA(1, 1);
  if constexpr (AUL == 2) { VMCNT(8); } else { VMCNT(6); }
  __builtin_amdgcn_s_barrier();
  __builtin_amdgcn_sched_barrier(0);
  loadA(aregA, 0, 0);
  loadB(breg0, 0, 0);

  for (int s = 0; s < KT; ++s) {
    if (s >= 1 && s + 1 < KT) stB(0, s + 1);
    loadB(breg1, 1, s);
    PHASE_MFMA(0, 0, aregA, breg0);
    if (s + 1 < KT) {
      if constexpr (AUL == 2) { VMCNT(6); } else { VMCNT(5); }
    } else {
      VMCNT(0);
    }
    __builtin_amdgcn_s_barrier();
    __builtin_amdgcn_sched_barrier(0);

    if (s >= 1 && s + 1 < KT) stA(1, s + 1);
    loadA(aregB, 1, s);
    PHASE_MFMA(0, 1, aregA, breg1);
    __builtin_amdgcn_s_barrier();
    __builtin_amdgcn_sched_barrier(0);

    if (s + 2 < KT) stA(0, s + 2);
    PHASE_MFMA(1, 1, aregB, breg1);
    if (s + 2 < KT) {
      if constexpr (AUL == 2) { VMCNT(4); } else { VMCNT(2); }
    } else if (s + 1 < KT) {
      if constexpr (AUL == 2) { VMCNT(2); } else { VMCNT(1); }
    } else {
      VMCNT(0);
    }
    __builtin_amdgcn_s_barrier();
    __builtin_amdgcn_sched_barrier(0);

    if (s + 2 < KT) stB(1, s + 2);
    PHASE_MFMA(1, 0, aregB, breg0);
    if (s + 1 < KT) {
      loadA(aregA, 0, s + 1);
      loadB(breg0, 0, s + 1);
    }
    __builtin_amdgcn_s_barrier();
    __builtin_amdgcn_sched_barrier(0);
  }

#undef PHASE_MFMA

  if constexpr (LNFUSE) {
    float (*s1p)[4] = (float(*)[4])((float*)lA);
    float (*s2p)[4] = (float(*)[4])((float*)lA + 512);
    float (*n2p)[4] = (float(*)[4])((float*)lA + 1024);

    float v[2][2][MI][2][4];
    float gg[2][2], bb[2][2];
    #pragma unroll
    for (int nh = 0; nh < 2; ++nh)
      #pragma unroll
      for (int ni = 0; ni < 2; ++ni) {
        int c = nh * 128 + wc * 32 + ni * 16 + fl;
        float bv = bias[c];
        gg[nh][ni] = lng[c]; bb[nh][ni] = lnb[c];
        #pragma unroll
        for (int mh = 0; mh < 2; ++mh)
          #pragma unroll
          for (int mi = 0; mi < MI; ++mi)
            #pragma unroll
            for (int r = 0; r < 4; ++r)
              v[mh][nh][mi][ni][r] = acc[mh][nh][mi][ni][r] + bv;
      }

    #pragma unroll
    for (int mh = 0; mh < 2; ++mh)
      #pragma unroll
      for (int mi = 0; mi < MI; ++mi)
        #pragma unroll
        for (int r = 0; r < 4; ++r) {
          float s1 = 0.0f, s2 = 0.0f;
          #pragma unroll
          for (int nh = 0; nh < 2; ++nh)
            #pragma unroll
            for (int ni = 0; ni < 2; ++ni) {
              float x = v[mh][nh][mi][ni][r];
              s1 += x; s2 += x * x;
            }
          for (int m = 1; m < 16; m <<= 1) {
            s1 += __shfl_xor(s1, m, 64);
            s2 += __shfl_xor(s2, m, 64);
          }
          if (fl == 0) {
            int lr = mh * 64 + wr * 32 + mi * 16 + fh * 4 + r;
            s1p[lr][wc] = s1; s2p[lr][wc] = s2;
          }
        }
    __syncthreads();

    float n2loc[2][MI][4];
    #pragma unroll
    for (int mh = 0; mh < 2; ++mh)
      #pragma unroll
      for (int mi = 0; mi < MI; ++mi)
        #pragma unroll
        for (int r = 0; r < 4; ++r) {
          int lr = mh * 64 + wr * 32 + mi * 16 + fh * 4 + r;
          float t1 = s1p[lr][0] + s1p[lr][1] + s1p[lr][2] + s1p[lr][3];
          float t2 = s2p[lr][0] + s2p[lr][1] + s2p[lr][2] + s2p[lr][3];
          float mu = t1 * (1.0f / PDIM);
          float var = t2 * (1.0f / PDIM) - mu * mu;
          float rstd = rsqrtf(var + 1e-5f);
          float n2 = 0.0f;
          #pragma unroll
          for (int nh = 0; nh < 2; ++nh)
            #pragma unroll
            for (int ni = 0; ni < 2; ++ni) {
              float y = (v[mh][nh][mi][ni][r] - mu) * rstd * gg[nh][ni] + bb[nh][ni];
              v[mh][nh][mi][ni][r] = y;
              n2 += y * y;
            }
          for (int m = 1; m < 16; m <<= 1) n2 += __shfl_xor(n2, m, 64);
          n2loc[mh][mi][r] = n2;
        }
    #pragma unroll
    for (int mh = 0; mh < 2; ++mh)
      #pragma unroll
      for (int mi = 0; mi < MI; ++mi)
        #pragma unroll
        for (int r = 0; r < 4; ++r)
          if (fl == 0) {
            int lr = mh * 64 + wr * 32 + mi * 16 + fh * 4 + r;
            n2p[lr][wc] = n2loc[mh][mi][r];
          }
    __syncthreads();

    #pragma unroll
    for (int mh = 0; mh < 2; ++mh)
      #pragma unroll
      for (int mi = 0; mi < MI; ++mi)
        #pragma unroll
        for (int r = 0; r < 4; ++r) {
          int lr = mh * 64 + wr * 32 + mi * 16 + fh * 4 + r;
          float t = n2p[lr][0] + n2p[lr][1] + n2p[lr][2] + n2p[lr][3];
          float sc = 1.0f / fmaxf(sqrtf(t), 1e-12f);
          #pragma unroll
          for (int nh = 0; nh < 2; ++nh)
            #pragma unroll
            for (int ni = 0; ni < 2; ++ni) {
              int c = nh * 128 + wc * 32 + ni * 16 + fl;
              ((float*)Cv)[(mrow0 + lr) * NDIM + c] = v[mh][nh][mi][ni][r] * sc;
            }
        }
  } else {
    #pragma unroll
    for (int mh = 0; mh < 2; ++mh)
      #pragma unroll
      for (int nh = 0; nh < 2; ++nh)
        #pragma unroll
        for (int ni = 0; ni < 2; ++ni) {
          int col = ncol0 + nh * 128 + wc * 32 + ni * 16 + fl;
          float bv = bias[col];
          #pragma unroll
          for (int mi = 0; mi < MI; ++mi)
            #pragma unroll
            for (int r = 0; r < 4; ++r) {
              long row = mrow0 + mh * BMH + wr * (BMH / 2) + mi * 16 + fh * 4 + r;
              float x = acc[mh][nh][mi][ni][r] + bv;
              if constexpr (RELU_OUT) {
                x = fmaxf(x, 0.0f);
                ((__bf16*)Cv)[row * NDIM + col] = (__bf16)x;
              } else {
                ((float*)Cv)[row * NDIM + col] = x;
              }
            }
        }
  }
}

// ---------------------------------------------------------------------------
// Per-row contrastive loss. One wave per row; 16-lane groups handle 4 negs
// at a time; negatives read as bf16 (halves L2 gather traffic).
// ---------------------------------------------------------------------------
__global__ __launch_bounds__(256)
void loss_kernel(const float* __restrict__ X, const __bf16* __restrict__ negb,
                 const int* __restrict__ nidx, float* __restrict__ partials) {
  __shared__ float lsum[4];
  int b    = blockIdx.x * 4 + (threadIdx.x >> 6);
  int lane = threadIdx.x & 63;
  int g = lane >> 4, lg = lane & 15;

  const float* arow = X + (size_t)b * PDIM;
  const float* prow = X + (size_t)(BATCH + b) * PDIM;

  float a16[16];
  #pragma unroll
  for (int j = 0; j < 4; ++j) {
    f32x4 av = *(const f32x4*)(arow + lg * 16 + j * 4);
    #pragma unroll
    for (int e = 0; e < 4; ++e) a16[j * 4 + e] = av[e];
  }

  float ps = 0.0f;
  #pragma unroll
  for (int j = 0; j < 4; ++j) {
    f32x4 p = *(const f32x4*)(prow + lg * 16 + j * 4);
    #pragma unroll
    for (int e = 0; e < 4; ++e) ps += a16[j * 4 + e] * p[e];
  }
  for (int m = 1; m < 16; m <<= 1) ps += __shfl_xor(ps, m, 64);
  float pos = ps * 2.0f;  // /TEMPERATURE

  float myneg = -3.0e38f;
  for (int k4 = 0; k4 < 16; ++k4) {
    int k = k4 * 4 + g;
    int idx = nidx[(size_t)b * KNEG + k];
    const __bf16* nrow = negb + (size_t)idx * PDIM;
    float sv = 0.0f;
    #pragma unroll
    for (int j = 0; j < 2; ++j) {
      bf16x8 nv = *(const bf16x8*)(nrow + lg * 16 + j * 8);
      #pragma unroll
      for (int e = 0; e < 8; ++e) sv += a16[j * 8 + e] * (float)nv[e];
    }
    for (int m = 1; m < 16; m <<= 1) sv += __shfl_xor(sv, m, 64);
    if (lg == k4) myneg = sv * 2.0f;
  }

  float mx = myneg;
  for (int m = 1; m < 64; m <<= 1) mx = fmaxf(mx, __shfl_xor(mx, m, 64));
  mx = fmaxf(mx, pos);
  float e = expf(myneg - mx);
  for (int m = 1; m < 64; m <<= 1) e += __shfl_xor(e, m, 64);
  float tot = e + expf(pos - mx);
  float lb = -(pos - mx - logf(tot));

  if (lane == 0) lsum[threadIdx.x >> 6] = lb;
  __syncthreads();
  if (threadIdx.x == 0)
    partials[blockIdx.x] = lsum[0] + lsum[1] + lsum[2] + lsum[3];
}

__global__ void finalize_kernel(const float* __restrict__ partials,
                                float* __restrict__ out) {
  __shared__ float ls[4];
  int tid = threadIdx.x;
  float s = 0.0f;
  for (int i = tid; i < 4096; i += 256) s += partials[i];
  for (int m = 1; m < 64; m <<= 1) s += __shfl_xor(s, m, 64);
  if ((tid & 63) == 0) ls[tid >> 6] = s;
  __syncthreads();
  if (tid == 0) out[0] = (ls[0] + ls[1] + ls[2] + ls[3]) * (1.0f / BATCH);
}

// ---------------------------------------------------------------------------
extern "C" void kernel_launch(void* const* d_in, const int* in_sizes, int n_in,
                              void* d_out, int out_size, void* d_ws, size_t ws_size,
                              hipStream_t stream) {
  const float* hidden   = (const float*)d_in[0];
  const float* positive = (const float*)d_in[1];
  const float* negbuf   = (const float*)d_in[2];
  const float* W1       = (const float*)d_in[3];
  const float* b1       = (const float*)d_in[4];
  const float* W2       = (const float*)d_in[5];
  const float* b2       = (const float*)d_in[6];
  const float* gamma    = (const float*)d_in[7];
  const float* beta     = (const float*)d_in[8];
  const int*   nidx     = (const int*)d_in[9];
  float* out = (float*)d_out;

  char* ws = (char*)d_ws;
  // Layout (~105 MiB; ws proven >= 206 MiB in rounds 2-14):
  //   Y1  [32768][1024] bf16 @ 0       (64 MiB)
  //   W1T                    @ 64 MiB  ( 4 MiB)
  //   W2T                              (0.5 MiB)
  //   negb [2000][256] bf16            ( 1 MiB)
  //   partials [4096] f32              (16 KiB)
  //   X   [32768][256] f32             (32 MiB)
  const size_t OFF_W1T  = 67108864;
  const size_t OFF_W2T  = OFF_W1T + 4194304;
  const size_t OFF_NEGB = OFF_W2T + 524288;
  const size_t OFF_PART = OFF_NEGB + 1048576;
  const size_t OFF_X    = OFF_PART + 16384;

  __bf16* Y1       = (__bf16*)(ws);
  __bf16* W1T      = (__bf16*)(ws + OFF_W1T);
  __bf16* W2T      = (__bf16*)(ws + OFF_W2T);
  __bf16* negb     = (__bf16*)(ws + OFF_NEGB);
  float*  partials = (float*) (ws + OFF_PART);
  float*  X        = (float*) (ws + OFF_X);

  transpose_cast_kernel<<<dim3(HHDIM / 32, HDIM / 32), dim3(32, 8), 0, stream>>>(
      W1, W1T, HDIM, HHDIM);
  transpose_cast_kernel<<<dim3(PDIM / 32, HHDIM / 32), dim3(32, 8), 0, stream>>>(
      W2, W2T, HHDIM, PDIM);
  cast_bf16_kernel<<<256, 256, 0, stream>>>(negbuf, negb, (long)NBUF * PDIM / 8);

  // GEMM1: fp32 A (hidden|positive) @ W1T^T + b1, relu -> Y1 (bf16).
  // A staged raw f32 via gload_lds; cast fused at ds_read->MFMA boundary.
  gemm_f32a<HDIM, HHDIM / 256, (M1 / 256) * (HHDIM / 256)>
      <<<(M1 / 256) * (HHDIM / 256), 512, 0, stream>>>(
          hidden, positive, W1T, b1, Y1);

  // GEMM2: Y1 @ W2T^T + b2, fused LayerNorm + L2-normalize -> X (f32).
  gemm_8ph<HHDIM, 64, PDIM / 256, false, true, (M1 / 128) * (PDIM / 256)>
      <<<(M1 / 128) * (PDIM / 256), 512, 0, stream>>>(
          Y1, W2T, b2, gamma, beta, X);

  loss_kernel<<<BATCH / 4, 256, 0, stream>>>(X, negb, nidx, partials);
  finalize_kernel<<<1, 256, 0, stream>>>(partials, out);
}

// Round 16
// 293.315 us; speedup vs baseline: 1.1141x; 1.0504x over previous
//
#include <hip/hip_runtime.h>
#include <hip/hip_bf16.h>
#include <cstdint>

// Problem constants
#define BATCH   16384
#define HDIM    2048
#define HHDIM   1024
#define PDIM    256
#define KNEG    64
#define NBUF    2000
#define M1      (2 * BATCH)          // 32768 rows through the projection head

typedef float  f32x4  __attribute__((ext_vector_type(4)));
typedef __bf16 bf16x8 __attribute__((ext_vector_type(8)));

typedef __attribute__((address_space(3))) unsigned int       lds_u32;
typedef __attribute__((address_space(1))) const unsigned int glb_u32;

__device__ __forceinline__ void gload_lds16(const void* g, void* l) {
  __builtin_amdgcn_global_load_lds((glb_u32*)g, (lds_u32*)l, 16, 0, 0);
}

#define VMCNT(n) asm volatile("s_waitcnt vmcnt(" #n ")" ::: "memory")
#define LGKM(n)  asm volatile("s_waitcnt lgkmcnt(" #n ")" ::: "memory")

// ---------------------------------------------------------------------------
// f32 -> bf16 cast, 8 elems/thread, grid-stride (used only for neg_buffer)
// ---------------------------------------------------------------------------
__global__ __launch_bounds__(256)
void cast_bf16_kernel(const float* __restrict__ src, __bf16* __restrict__ dst,
                      long n8) {
  long i = (long)blockIdx.x * blockDim.x + threadIdx.x;
  long stride = (long)gridDim.x * blockDim.x;
  for (; i < n8; i += stride) {
    f32x4 a = ((const f32x4*)src)[2 * i];
    f32x4 b = ((const f32x4*)src)[2 * i + 1];
    bf16x8 w;
    for (int j = 0; j < 4; ++j) { w[j] = (__bf16)a[j]; w[4 + j] = (__bf16)b[j]; }
    ((bf16x8*)dst)[i] = w;
  }
}

// ---------------------------------------------------------------------------
// Transpose + cast: src [K][N] f32 row-major  ->  dst [N][K] bf16 row-major
// ---------------------------------------------------------------------------
__global__ void transpose_cast_kernel(const float* __restrict__ src,
                                      __bf16* __restrict__ dst, int K, int N) {
  __shared__ float tile[32][33];
  int bn = blockIdx.x * 32, bk = blockIdx.y * 32;
  int tx = threadIdx.x, ty = threadIdx.y;  // 32 x 8
  for (int j = 0; j < 32; j += 8)
    tile[ty + j][tx] = src[(size_t)(bk + ty + j) * N + bn + tx];
  __syncthreads();
  for (int j = 0; j < 32; j += 8)
    dst[(size_t)(bn + ty + j) * K + bk + tx] = (__bf16)tile[tx][ty + j];
}

// ---------------------------------------------------------------------------
// gemm_f32a: 256x256 MFMA GEMM with fp32 A staged RAW into LDS (cast-free).
//   C = A(f32)[M][KD] @ Bt(bf16)[NBt*256][KD]^T + bias, relu, bf16 store.
//
//   r16 BANK FIX: r15's A-reads used pre-XOR slots {2fh, 2fh+1} and measured
//   SQ_LDS_BANK_CONFLICT = 1.678e7 (= +4.0 cyc per A ds_read_b128). The
//   gemm_8ph pattern -- pre-XOR slot {p*4 + fh} -- measured ZERO across 4
//   rounds at identical rows/strides. We therefore PERMUTE the K-chunk
//   storage order within each 128B row: chunk c stored at slot
//   sigma(c) = (c>>1) + (c&1)*4, so the read slot becomes
//   (p*4 + fh) ^ (row&7) -- byte-identical bank behavior to the proven
//   pattern. Staging inverts sigma in the global source-chunk index:
//   sigma^-1(x) = 2*(x&3) + (x>>2). Pure relabeling -> correctness
//   unchanged (write/read self-consistent).
//
//   512 threads = 8 waves (2x4). BK=32, KT=64. LDS 96 KB:
//     lAf f32 [2 buf][2 half][128 rows x 8 chunk-slots] (64 KB)
//     lBf bf16 [2 buf][2 half][128x32] (32 KB), slot^((row>>1)&3) swizzle
//         [verified 0-conflict rounds 2/3/14]
//   Phases per step s (r6-verified skeleton):
//     p1 Q(0,0): ds_read A0 raw + B0; stage B0(s+1)[1]
//     p2 Q(0,1): ds_read B1;          stage A1(s+1)[2]
//     p3 Q(1,1): ds_read A1 raw;      stage A0(s+2)[2]
//     p4 Q(1,0): no reads;            stage B1(s+2)[1]
//   vmcnt ledger: prologue 12 loads, VMCNT(6) -> step 0 landed. End-p4(s):
//   outstanding 9; VMCNT(3) leaves {A0(s+2),B1(s+2)} -> step s+1 landed.
//   Edges: s+2>=KT -> VMCNT(0). Overwrite safety: stage targets' readers
//   drained (LGKM(0) before MFMA) >=2 barriers before the stage issue.
// ---------------------------------------------------------------------------
template <int KD, int NBt, int GRID>
__global__ __launch_bounds__(512)
void gemm_f32a(const float* __restrict__ A0, const float* __restrict__ A1v,
               const __bf16* __restrict__ Bt, const float* __restrict__ bias,
               __bf16* __restrict__ C) {
  constexpr int KT   = KD / 32;
  constexpr int NDIM = NBt * 256;

  __shared__ float  lAf[2 * 2 * 4096];   // 64 KB
  __shared__ __bf16 lBf[2 * 2 * 4096];   // 32 KB

  constexpr int Q = GRID / 8;            // XCD-bijective swizzle (GRID%8==0)
  int bid = blockIdx.x;
  int swb = (bid & 7) * Q + (bid >> 3);
  const int mb = swb / NBt, nb = swb % NBt;
  const long mrow0 = (long)mb * 256;
  const int  ncol0 = nb * 256;

  // block rows entirely within one input (256 | BATCH)
  const float* Af = (mrow0 < BATCH) ? (A0 + mrow0 * (long)KD)
                                    : (A1v + (mrow0 - BATCH) * (long)KD);

  const int tid = threadIdx.x;
  const int wid = tid >> 6, lane = tid & 63;
  const int wr = wid >> 2, wc = wid & 3;   // 2 x 4 wave grid
  const int fl = lane & 15, fh = lane >> 4;

  // A fragment read offsets (f32 elems, half-relative). Lane (fl,fh) needs
  // global K-chunks c = {2fh, 2fh+1}; with storage permutation sigma the
  // read slot for p is (p*4 + fh) ^ (row&7)  [8ph-proven bank pattern].
  int aoffs[4][2];
  #pragma unroll
  for (int mi = 0; mi < 4; ++mi)
    #pragma unroll
    for (int p = 0; p < 2; ++p) {
      int row = wr * 64 + mi * 16 + fl;
      aoffs[mi][p] = row * 32 + (((p * 4 + fh) ^ (row & 7)) * 4);
    }
  // B fragment read offsets (bf16 elems, half-relative)
  int boffs[2];
  #pragma unroll
  for (int ni = 0; ni < 2; ++ni) {
    int row = wc * 32 + ni * 16 + fl;
    boffs[ni] = row * 32 + ((fh ^ ((row >> 1) & 3)) * 8);
  }

  // Staging (pre-swizzled global source -> linear LDS dest)
  // A: thread t -> dest (row R=t>>3, slot S=t&7); stored content must be
  // global chunk c = sigma^-1(S ^ (R&7)), sigma^-1(x) = 2*(x&3) + (x>>2).
  const int r0a = tid >> 3;
  const int xa  = (tid & 7) ^ ((tid >> 3) & 7);
  const int ca  = 2 * (xa & 3) + (xa >> 2);
  const int r0b = tid >> 2, ssb = (tid & 3) ^ (((tid >> 2) >> 1) & 3);
  const int dwA = wid * 256;   // f32 elems (wave-uniform 1 KB chunk)
  const int dwB = wid * 512;   // bf16 elems

  auto stA = [&](int h, int t) {   // 2 loads (rows r0a, r0a+64; same row&7)
    float* base = lAf + (t & 1) * 8192 + h * 4096 + dwA;
    const float* s0 = Af + (size_t)(h * 128 + r0a) * KD + t * 32 + ca * 4;
    gload_lds16(s0, (void*)base);
    gload_lds16(s0 + (size_t)64 * KD, (void*)(base + 2048));
  };
  auto stB = [&](int h, int t) {   // 1 load
    __bf16* base = lBf + (t & 1) * 8192 + h * 4096 + dwB;
    gload_lds16(Bt + (size_t)(ncol0 + h * 128 + r0b) * KD + t * 32 + ssb * 8,
                (void*)base);
  };

  f32x4  aA[4][2];                 // raw f32 A fragments
  bf16x8 areg[4], breg0[2], breg1[2];

  auto loadAraw = [&](int mh, int s) {
    const float* base = lAf + (s & 1) * 8192 + mh * 4096;
    #pragma unroll
    for (int mi = 0; mi < 4; ++mi)
      #pragma unroll
      for (int p = 0; p < 2; ++p)
        aA[mi][p] = *(const f32x4*)(base + aoffs[mi][p]);
  };
  auto cvtA = [&]() {
    #pragma unroll
    for (int mi = 0; mi < 4; ++mi)
      #pragma unroll
      for (int j = 0; j < 4; ++j) {
        areg[mi][j]     = (__bf16)aA[mi][0][j];
        areg[mi][4 + j] = (__bf16)aA[mi][1][j];
      }
  };
  auto loadB = [&](bf16x8 (&br)[2], int nh, int s) {
    const __bf16* base = lBf + (s & 1) * 8192 + nh * 4096;
    #pragma unroll
    for (int ni = 0; ni < 2; ++ni)
      br[ni] = *(const bf16x8*)(base + boffs[ni]);
  };

  f32x4 acc[2][2][4][2] = {};

#define QMFMA(mh, nh, BR)                                                     \
  __builtin_amdgcn_s_setprio(1);                                              \
  _Pragma("unroll")                                                           \
  for (int mi = 0; mi < 4; ++mi) {                                            \
    _Pragma("unroll")                                                         \
    for (int ni = 0; ni < 2; ++ni)                                            \
      acc[mh][nh][mi][ni] = __builtin_amdgcn_mfma_f32_16x16x32_bf16(          \
          areg[mi], BR[ni], acc[mh][nh][mi][ni], 0, 0, 0);                    \
  }                                                                           \
  __builtin_amdgcn_s_setprio(0);

  // Prologue: stage steps 0 and 1 (12 loads); leave step-1's 6 in flight.
  stA(0, 0); stB(0, 0); stA(1, 0); stB(1, 0);
  stA(0, 1); stB(1, 1); stB(0, 1); stA(1, 1);
  VMCNT(6);
  __builtin_amdgcn_s_barrier();
  __builtin_amdgcn_sched_barrier(0);

  for (int s = 0; s < KT; ++s) {
    // ---- p1: Q(0,0)
    loadAraw(0, s);
    loadB(breg0, 0, s);
    if (s >= 1 && s + 1 < KT) stB(0, s + 1);
    __builtin_amdgcn_s_barrier();
    LGKM(0);
    __builtin_amdgcn_sched_barrier(0);
    cvtA();
    QMFMA(0, 0, breg0);
    __builtin_amdgcn_s_barrier();

    // ---- p2: Q(0,1)
    loadB(breg1, 1, s);
    if (s >= 1 && s + 1 < KT) stA(1, s + 1);
    __builtin_amdgcn_s_barrier();
    LGKM(0);
    __builtin_amdgcn_sched_barrier(0);
    QMFMA(0, 1, breg1);
    __builtin_amdgcn_s_barrier();

    // ---- p3: Q(1,1)
    loadAraw(1, s);
    if (s + 2 < KT) stA(0, s + 2);
    __builtin_amdgcn_s_barrier();
    LGKM(0);
    __builtin_amdgcn_sched_barrier(0);
    cvtA();
    QMFMA(1, 1, breg1);
    __builtin_amdgcn_s_barrier();

    // ---- p4: Q(1,0) (no reads; breg0/areg held)
    if (s + 2 < KT) stB(1, s + 2);
    __builtin_amdgcn_s_barrier();
    __builtin_amdgcn_sched_barrier(0);
    QMFMA(1, 0, breg0);
    if (s + 2 < KT) { VMCNT(3); } else { VMCNT(0); }
    __builtin_amdgcn_s_barrier();
    __builtin_amdgcn_sched_barrier(0);
  }

#undef QMFMA

  // Epilogue: bias + relu + bf16 store
  #pragma unroll
  for (int mh = 0; mh < 2; ++mh)
    #pragma unroll
    for (int nh = 0; nh < 2; ++nh)
      #pragma unroll
      for (int ni = 0; ni < 2; ++ni) {
        int col = ncol0 + nh * 128 + wc * 32 + ni * 16 + fl;
        float bv = bias[col];
        #pragma unroll
        for (int mi = 0; mi < 4; ++mi)
          #pragma unroll
          for (int r = 0; r < 4; ++r) {
            long row = mrow0 + mh * 128 + wr * 64 + mi * 16 + fh * 4 + r;
            float v = fmaxf(acc[mh][nh][mi][ni][r] + bv, 0.0f);
            C[row * NDIM + col] = (__bf16)v;
          }
      }
}

// ---------------------------------------------------------------------------
// Pipelined-read 8-phase (2*BMH)x256 MFMA GEMM -- r10-verified, used for GEMM2.
// ---------------------------------------------------------------------------
template <int KD, int BMH, int NBt, bool RELU_OUT, bool LNFUSE, int GRID>
__global__ __launch_bounds__(512)
void gemm_8ph(const __bf16* __restrict__ A, const __bf16* __restrict__ Bt,
              const float* __restrict__ bias,
              const float* __restrict__ lng, const float* __restrict__ lnb,
              void* __restrict__ Cv) {
  static_assert(!LNFUSE || NBt == 1, "LN fusion needs full rows per block");
  constexpr int KT    = KD / 64;
  constexpr int MI    = BMH / 32;
  constexpr int AHALF = BMH * 64;
  constexpr int BHALF = 128 * 64;
  constexpr int ASTEP = 2 * AHALF;
  constexpr int BSTEP = 2 * BHALF;
  constexpr int NDIM  = NBt * 256;
  constexpr int AUL   = BMH / 64;

  __shared__ __bf16 lA[2 * ASTEP];
  __shared__ __bf16 lB[2 * BSTEP];

  constexpr int Q = GRID / 8;
  int bid = blockIdx.x;
  int swb = (bid & 7) * Q + (bid >> 3);
  const int mb = swb / NBt, nb = swb % NBt;
  const long mrow0 = (long)mb * (2 * BMH);
  const int  ncol0 = nb * 256;

  const int tid = threadIdx.x;
  const int wid = tid >> 6, lane = tid & 63;
  const int wr = wid >> 2, wc = wid & 3;
  const int fl = lane & 15, fh = lane >> 4;

  int aoff[MI][2], boff[2][2];
  #pragma unroll
  for (int mi = 0; mi < MI; ++mi)
    #pragma unroll
    for (int ks = 0; ks < 2; ++ks) {
      int row = wr * (BMH / 2) + mi * 16 + fl;
      aoff[mi][ks] = row * 64 + (((ks * 4 + fh) ^ (row & 7)) * 8);
    }
  #pragma unroll
  for (int ni = 0; ni < 2; ++ni)
    #pragma unroll
    for (int ks = 0; ks < 2; ++ks) {
      int row = wc * 32 + ni * 16 + fl;
      boff[ni][ks] = row * 64 + (((ks * 4 + fh) ^ (row & 7)) * 8);
    }

  const int r0 = tid >> 3, sl = tid & 7;
  long aS[2][AUL], bS[2][2];
  #pragma unroll
  for (int h = 0; h < 2; ++h) {
    #pragma unroll
    for (int i = 0; i < AUL; ++i) {
      int rr = r0 + i * 64;
      int ss = sl ^ (rr & 7);
      aS[h][i] = (mrow0 + h * BMH + rr) * (long)KD + ss * 8;
    }
    #pragma unroll
    for (int i = 0; i < 2; ++i) {
      int rr = r0 + i * 64;
      int ss = sl ^ (rr & 7);
      bS[h][i] = ((long)(ncol0 + h * 128 + rr)) * KD + ss * 8;
    }
  }
  const int dstw = wid * 512;

  auto stA = [&](int h, int t) {
    __bf16* base = lA + (t & 1) * ASTEP + h * AHALF + dstw;
    #pragma unroll
    for (int i = 0; i < AUL; ++i)
      gload_lds16(A + aS[h][i] + (long)t * 64, (void*)(base + i * 4096));
  };
  auto stB = [&](int h, int t) {
    __bf16* base = lB + (t & 1) * BSTEP + h * BHALF + dstw;
    #pragma unroll
    for (int i = 0; i < 2; ++i)
      gload_lds16(Bt + bS[h][i] + (long)t * 64, (void*)(base + i * 4096));
  };

  bf16x8 aregA[MI][2], aregB[MI][2], breg0[2][2], breg1[2][2];
  auto loadA = [&](bf16x8 (&ar)[MI][2], int mh, int s) {
    const __bf16* base = lA + (s & 1) * ASTEP + mh * AHALF;
    #pragma unroll
    for (int mi = 0; mi < MI; ++mi)
      #pragma unroll
      for (int ks = 0; ks < 2; ++ks)
        ar[mi][ks] = *(const bf16x8*)(base + aoff[mi][ks]);
  };
  auto loadB = [&](bf16x8 (&br)[2][2], int nh, int s) {
    const __bf16* base = lB + (s & 1) * BSTEP + nh * BHALF;
    #pragma unroll
    for (int ni = 0; ni < 2; ++ni)
      #pragma unroll
      for (int ks = 0; ks < 2; ++ks)
        br[ni][ks] = *(const bf16x8*)(base + boff[ni][ks]);
  };

  f32x4 acc[2][2][MI][2] = {};

#define PHASE_MFMA(mh, nh, AR, BR)                                            \
  __builtin_amdgcn_s_setprio(1);                                              \
  _Pragma("unroll")                                                           \
  for (int ks = 0; ks < 2; ++ks) {                                            \
    _Pragma("unroll")                                                         \
    for (int mi = 0; mi < MI; ++mi) {                                         \
      _Pragma("unroll")                                                       \
      for (int ni = 0; ni < 2; ++ni)                                          \
        acc[mh][nh][mi][ni] = __builtin_amdgcn_mfma_f32_16x16x32_bf16(        \
            AR[mi][ks], BR[ni][ks], acc[mh][nh][mi][ni], 0, 0, 0);            \
    }                                                                         \
  }                                                                           \
  __builtin_amdgcn_s_setprio(0);

  stA(0, 0); stB(0, 0); stA(1, 0); stB(1, 0);
  stA(0, 1); stB(1, 1); stB(0, 1); stA(1, 1);
  if constexpr (AUL == 2) { VMCNT(8); } else { VMCNT(6); }
  __builtin_amdgcn_s_barrier();
  __builtin_amdgcn_sched_barrier(0);
  loadA(aregA, 0, 0);
  loadB(breg0, 0, 0);

  for (int s = 0; s < KT; ++s) {
    if (s >= 1 && s + 1 < KT) stB(0, s + 1);
    loadB(breg1, 1, s);
    PHASE_MFMA(0, 0, aregA, breg0);
    if (s + 1 < KT) {
      if constexpr (AUL == 2) { VMCNT(6); } else { VMCNT(5); }
    } else {
      VMCNT(0);
    }
    __builtin_amdgcn_s_barrier();
    __builtin_amdgcn_sched_barrier(0);

    if (s >= 1 && s + 1 < KT) stA(1, s + 1);
    loadA(aregB, 1, s);
    PHASE_MFMA(0, 1, aregA, breg1);
    __builtin_amdgcn_s_barrier();
    __builtin_amdgcn_sched_barrier(0);

    if (s + 2 < KT) stA(0, s + 2);
    PHASE_MFMA(1, 1, aregB, breg1);
    if (s + 2 < KT) {
      if constexpr (AUL == 2) { VMCNT(4); } else { VMCNT(2); }
    } else if (s + 1 < KT) {
      if constexpr (AUL == 2) { VMCNT(2); } else { VMCNT(1); }
    } else {
      VMCNT(0);
    }
    __builtin_amdgcn_s_barrier();
    __builtin_amdgcn_sched_barrier(0);

    if (s + 2 < KT) stB(1, s + 2);
    PHASE_MFMA(1, 0, aregB, breg0);
    if (s + 1 < KT) {
      loadA(aregA, 0, s + 1);
      loadB(breg0, 0, s + 1);
    }
    __builtin_amdgcn_s_barrier();
    __builtin_amdgcn_sched_barrier(0);
  }

#undef PHASE_MFMA

  if constexpr (LNFUSE) {
    float (*s1p)[4] = (float(*)[4])((float*)lA);
    float (*s2p)[4] = (float(*)[4])((float*)lA + 512);
    float (*n2p)[4] = (float(*)[4])((float*)lA + 1024);

    float v[2][2][MI][2][4];
    float gg[2][2], bb[2][2];
    #pragma unroll
    for (int nh = 0; nh < 2; ++nh)
      #pragma unroll
      for (int ni = 0; ni < 2; ++ni) {
        int c = nh * 128 + wc * 32 + ni * 16 + fl;
        float bv = bias[c];
        gg[nh][ni] = lng[c]; bb[nh][ni] = lnb[c];
        #pragma unroll
        for (int mh = 0; mh < 2; ++mh)
          #pragma unroll
          for (int mi = 0; mi < MI; ++mi)
            #pragma unroll
            for (int r = 0; r < 4; ++r)
              v[mh][nh][mi][ni][r] = acc[mh][nh][mi][ni][r] + bv;
      }

    #pragma unroll
    for (int mh = 0; mh < 2; ++mh)
      #pragma unroll
      for (int mi = 0; mi < MI; ++mi)
        #pragma unroll
        for (int r = 0; r < 4; ++r) {
          float s1 = 0.0f, s2 = 0.0f;
          #pragma unroll
          for (int nh = 0; nh < 2; ++nh)
            #pragma unroll
            for (int ni = 0; ni < 2; ++ni) {
              float x = v[mh][nh][mi][ni][r];
              s1 += x; s2 += x * x;
            }
          for (int m = 1; m < 16; m <<= 1) {
            s1 += __shfl_xor(s1, m, 64);
            s2 += __shfl_xor(s2, m, 64);
          }
          if (fl == 0) {
            int lr = mh * 64 + wr * 32 + mi * 16 + fh * 4 + r;
            s1p[lr][wc] = s1; s2p[lr][wc] = s2;
          }
        }
    __syncthreads();

    float n2loc[2][MI][4];
    #pragma unroll
    for (int mh = 0; mh < 2; ++mh)
      #pragma unroll
      for (int mi = 0; mi < MI; ++mi)
        #pragma unroll
        for (int r = 0; r < 4; ++r) {
          int lr = mh * 64 + wr * 32 + mi * 16 + fh * 4 + r;
          float t1 = s1p[lr][0] + s1p[lr][1] + s1p[lr][2] + s1p[lr][3];
          float t2 = s2p[lr][0] + s2p[lr][1] + s2p[lr][2] + s2p[lr][3];
          float mu = t1 * (1.0f / PDIM);
          float var = t2 * (1.0f / PDIM) - mu * mu;
          float rstd = rsqrtf(var + 1e-5f);
          float n2 = 0.0f;
          #pragma unroll
          for (int nh = 0; nh < 2; ++nh)
            #pragma unroll
            for (int ni = 0; ni < 2; ++ni) {
              float y = (v[mh][nh][mi][ni][r] - mu) * rstd * gg[nh][ni] + bb[nh][ni];
              v[mh][nh][mi][ni][r] = y;
              n2 += y * y;
            }
          for (int m = 1; m < 16; m <<= 1) n2 += __shfl_xor(n2, m, 64);
          n2loc[mh][mi][r] = n2;
        }
    #pragma unroll
    for (int mh = 0; mh < 2; ++mh)
      #pragma unroll
      for (int mi = 0; mi < MI; ++mi)
        #pragma unroll
        for (int r = 0; r < 4; ++r)
          if (fl == 0) {
            int lr = mh * 64 + wr * 32 + mi * 16 + fh * 4 + r;
            n2p[lr][wc] = n2loc[mh][mi][r];
          }
    __syncthreads();

    #pragma unroll
    for (int mh = 0; mh < 2; ++mh)
      #pragma unroll
      for (int mi = 0; mi < MI; ++mi)
        #pragma unroll
        for (int r = 0; r < 4; ++r) {
          int lr = mh * 64 + wr * 32 + mi * 16 + fh * 4 + r;
          float t = n2p[lr][0] + n2p[lr][1] + n2p[lr][2] + n2p[lr][3];
          float sc = 1.0f / fmaxf(sqrtf(t), 1e-12f);
          #pragma unroll
          for (int nh = 0; nh < 2; ++nh)
            #pragma unroll
            for (int ni = 0; ni < 2; ++ni) {
              int c = nh * 128 + wc * 32 + ni * 16 + fl;
              ((float*)Cv)[(mrow0 + lr) * NDIM + c] = v[mh][nh][mi][ni][r] * sc;
            }
        }
  } else {
    #pragma unroll
    for (int mh = 0; mh < 2; ++mh)
      #pragma unroll
      for (int nh = 0; nh < 2; ++nh)
        #pragma unroll
        for (int ni = 0; ni < 2; ++ni) {
          int col = ncol0 + nh * 128 + wc * 32 + ni * 16 + fl;
          float bv = bias[col];
          #pragma unroll
          for (int mi = 0; mi < MI; ++mi)
            #pragma unroll
            for (int r = 0; r < 4; ++r) {
              long row = mrow0 + mh * BMH + wr * (BMH / 2) + mi * 16 + fh * 4 + r;
              float x = acc[mh][nh][mi][ni][r] + bv;
              if constexpr (RELU_OUT) {
                x = fmaxf(x, 0.0f);
                ((__bf16*)Cv)[row * NDIM + col] = (__bf16)x;
              } else {
                ((float*)Cv)[row * NDIM + col] = x;
              }
            }
        }
  }
}

// ---------------------------------------------------------------------------
// Per-row contrastive loss. One wave per row; 16-lane groups handle 4 negs
// at a time; negatives read as bf16 (halves L2 gather traffic).
// ---------------------------------------------------------------------------
__global__ __launch_bounds__(256)
void loss_kernel(const float* __restrict__ X, const __bf16* __restrict__ negb,
                 const int* __restrict__ nidx, float* __restrict__ partials) {
  __shared__ float lsum[4];
  int b    = blockIdx.x * 4 + (threadIdx.x >> 6);
  int lane = threadIdx.x & 63;
  int g = lane >> 4, lg = lane & 15;

  const float* arow = X + (size_t)b * PDIM;
  const float* prow = X + (size_t)(BATCH + b) * PDIM;

  float a16[16];
  #pragma unroll
  for (int j = 0; j < 4; ++j) {
    f32x4 av = *(const f32x4*)(arow + lg * 16 + j * 4);
    #pragma unroll
    for (int e = 0; e < 4; ++e) a16[j * 4 + e] = av[e];
  }

  float ps = 0.0f;
  #pragma unroll
  for (int j = 0; j < 4; ++j) {
    f32x4 p = *(const f32x4*)(prow + lg * 16 + j * 4);
    #pragma unroll
    for (int e = 0; e < 4; ++e) ps += a16[j * 4 + e] * p[e];
  }
  for (int m = 1; m < 16; m <<= 1) ps += __shfl_xor(ps, m, 64);
  float pos = ps * 2.0f;  // /TEMPERATURE

  float myneg = -3.0e38f;
  for (int k4 = 0; k4 < 16; ++k4) {
    int k = k4 * 4 + g;
    int idx = nidx[(size_t)b * KNEG + k];
    const __bf16* nrow = negb + (size_t)idx * PDIM;
    float sv = 0.0f;
    #pragma unroll
    for (int j = 0; j < 2; ++j) {
      bf16x8 nv = *(const bf16x8*)(nrow + lg * 16 + j * 8);
      #pragma unroll
      for (int e = 0; e < 8; ++e) sv += a16[j * 8 + e] * (float)nv[e];
    }
    for (int m = 1; m < 16; m <<= 1) sv += __shfl_xor(sv, m, 64);
    if (lg == k4) myneg = sv * 2.0f;
  }

  float mx = myneg;
  for (int m = 1; m < 64; m <<= 1) mx = fmaxf(mx, __shfl_xor(mx, m, 64));
  mx = fmaxf(mx, pos);
  float e = expf(myneg - mx);
  for (int m = 1; m < 64; m <<= 1) e += __shfl_xor(e, m, 64);
  float tot = e + expf(pos - mx);
  float lb = -(pos - mx - logf(tot));

  if (lane == 0) lsum[threadIdx.x >> 6] = lb;
  __syncthreads();
  if (threadIdx.x == 0)
    partials[blockIdx.x] = lsum[0] + lsum[1] + lsum[2] + lsum[3];
}

__global__ void finalize_kernel(const float* __restrict__ partials,
                                float* __restrict__ out) {
  __shared__ float ls[4];
  int tid = threadIdx.x;
  float s = 0.0f;
  for (int i = tid; i < 4096; i += 256) s += partials[i];
  for (int m = 1; m < 64; m <<= 1) s += __shfl_xor(s, m, 64);
  if ((tid & 63) == 0) ls[tid >> 6] = s;
  __syncthreads();
  if (tid == 0) out[0] = (ls[0] + ls[1] + ls[2] + ls[3]) * (1.0f / BATCH);
}

// ---------------------------------------------------------------------------
extern "C" void kernel_launch(void* const* d_in, const int* in_sizes, int n_in,
                              void* d_out, int out_size, void* d_ws, size_t ws_size,
                              hipStream_t stream) {
  const float* hidden   = (const float*)d_in[0];
  const float* positive = (const float*)d_in[1];
  const float* negbuf   = (const float*)d_in[2];
  const float* W1       = (const float*)d_in[3];
  const float* b1       = (const float*)d_in[4];
  const float* W2       = (const float*)d_in[5];
  const float* b2       = (const float*)d_in[6];
  const float* gamma    = (const float*)d_in[7];
  const float* beta     = (const float*)d_in[8];
  const int*   nidx     = (const int*)d_in[9];
  float* out = (float*)d_out;

  char* ws = (char*)d_ws;
  // Layout (~105 MiB; ws proven >= 206 MiB in rounds 2-15):
  const size_t OFF_W1T  = 67108864;
  const size_t OFF_W2T  = OFF_W1T + 4194304;
  const size_t OFF_NEGB = OFF_W2T + 524288;
  const size_t OFF_PART = OFF_NEGB + 1048576;
  const size_t OFF_X    = OFF_PART + 16384;

  __bf16* Y1       = (__bf16*)(ws);
  __bf16* W1T      = (__bf16*)(ws + OFF_W1T);
  __bf16* W2T      = (__bf16*)(ws + OFF_W2T);
  __bf16* negb     = (__bf16*)(ws + OFF_NEGB);
  float*  partials = (float*) (ws + OFF_PART);
  float*  X        = (float*) (ws + OFF_X);

  transpose_cast_kernel<<<dim3(HHDIM / 32, HDIM / 32), dim3(32, 8), 0, stream>>>(
      W1, W1T, HDIM, HHDIM);
  transpose_cast_kernel<<<dim3(PDIM / 32, HHDIM / 32), dim3(32, 8), 0, stream>>>(
      W2, W2T, HHDIM, PDIM);
  cast_bf16_kernel<<<256, 256, 0, stream>>>(negbuf, negb, (long)NBUF * PDIM / 8);

  // GEMM1: fp32 A (hidden|positive) @ W1T^T + b1, relu -> Y1 (bf16).
  // A staged raw f32 via gload_lds; cast fused at ds_read->MFMA boundary.
  gemm_f32a<HDIM, HHDIM / 256, (M1 / 256) * (HHDIM / 256)>
      <<<(M1 / 256) * (HHDIM / 256), 512, 0, stream>>>(
          hidden, positive, W1T, b1, Y1);

  // GEMM2: Y1 @ W2T^T + b2, fused LayerNorm + L2-normalize -> X (f32).
  gemm_8ph<HHDIM, 64, PDIM / 256, false, true, (M1 / 128) * (PDIM / 256)>
      <<<(M1 / 128) * (PDIM / 256), 512, 0, stream>>>(
          Y1, W2T, b2, gamma, beta, X);

  loss_kernel<<<BATCH / 4, 256, 0, stream>>>(X, negb, nidx, partials);
  finalize_kernel<<<1, 256, 0, stream>>>(partials, out);
}